// Round 4
// baseline (143.503 us; speedup 1.0000x reference)
//
#include <hip/hip_runtime.h>
#include <math.h>

// N=500000 points, M=128 centers, D=16.
#define M_CTR 128
#define D_DIM 16
#define KSTEPS 10          // K = 160 = 10 x 16
#define NSLOT 80           // phi slots per lane-half (80 x 2 = 160 = K)
#define GRID_MAIN 4096
// ws layout: [0,40960) A-frags fp16 (40 frag-blocks x 1KB); [40960,41472) consts f32[128]
#define WS_CONST_F32_OFF 10240
#define LOG2E 1.4426950408889634f
#define LN2   0.6931471805599453f

typedef _Float16 half8 __attribute__((ext_vector_type(8)));
typedef float f32x16 __attribute__((ext_vector_type(16)));

// ---------------------------------------------------------------------------
// Slot table: maps frag slot s (= t*8+e, per lane-half) -> feature.
// Lane-half hi=0 takes (a,b) as-is; hi=1 applies sigma: +8 mod 16 (mode 0/2)
// or +4 (mode 1). modes: 0 = zs8[a]*zs8[b], 1 = z4l[a]*z4h[a], 2 = zs8[a], 3 = 0.
// ---------------------------------------------------------------------------
struct SlotTab { unsigned char a[NSLOT]; unsigned char b[NSLOT]; unsigned char m[NSLOT]; };
constexpr SlotTab make_tab() {
    SlotTab T{};
    int s = 0;
    for (int d = 0; d < 8; ++d) { T.a[s] = (unsigned char)d; T.b[s] = (unsigned char)d; T.m[s] = 0; ++s; }
    for (int d = 0; d < 8; ++d)
        for (int f = d + 1; f < 8; ++f) { T.a[s] = (unsigned char)d; T.b[s] = (unsigned char)f; T.m[s] = 0; ++s; }
    for (int d = 0; d < 8; ++d)
        for (int f2 = d + 1; f2 < 8; ++f2) { T.a[s] = (unsigned char)d; T.b[s] = (unsigned char)(f2 + 8); T.m[s] = 0; ++s; }
    for (int d = 0; d < 4; ++d) { T.a[s] = (unsigned char)d; T.b[s] = (unsigned char)(d + 8); T.m[s] = 1; ++s; }
    for (int d = 0; d < 8; ++d) { T.a[s] = (unsigned char)d; T.b[s] = 0; T.m[s] = 2; ++s; }
    for (; s < NSLOT; ++s) { T.a[s] = 0; T.b[s] = 0; T.m[s] = 3; }
    return T;
}
constexpr SlotTab TAB = make_tab();

// ---------------------------------------------------------------------------
// Prep: one 64-thread block per center j. All coefficients scaled by LOG2E
// so the main kernel works in the exp2/log2 domain (native v_exp/v_log).
// ---------------------------------------------------------------------------
__global__ __launch_bounds__(64) void gmm_prep_kernel(
    const float* __restrict__ centers,   // [M,16]
    const float* __restrict__ Lmat,      // [M,16,16]
    const float* __restrict__ weights,   // [M]
    float* __restrict__ ws)
{
    const int j    = blockIdx.x;
    const int lane = threadIdx.x;        // 0..63
    const int r    = lane & 15;

    __shared__ float S_lds[D_DIM][D_DIM + 1];
    __shared__ float Scp_lds[D_DIM];

    float Lr[D_DIM];
    {
        const float4* Lrow = (const float4*)(Lmat + (size_t)j * 256 + r * 16);
        #pragma unroll
        for (int q = 0; q < 4; ++q) {
            const float4 v = Lrow[q];
            Lr[q * 4 + 0] = v.x; Lr[q * 4 + 1] = v.y;
            Lr[q * 4 + 2] = v.z; Lr[q * 4 + 3] = v.w;
        }
    }

    // log|det L| via lane-parallel LU (L ~ 15I + 0.1*noise, diag dominant)
    float u[D_DIM];
    #pragma unroll
    for (int e = 0; e < D_DIM; ++e) u[e] = Lr[e];
    float logdet = 0.f;
    #pragma unroll
    for (int k = 0; k < D_DIM; ++k) {
        const float pk = __shfl(u[k], k);
        logdet += logf(fabsf(pk));
        const float f = u[k] * (1.0f / pk);
        #pragma unroll
        for (int c = k + 1; c < D_DIM; ++c) {
            const float rkc = __shfl(u[c], k);
            if (r > k) u[c] -= f * rkc;
        }
    }

    // S = L L^T
    #pragma unroll
    for (int f = 0; f < D_DIM; ++f) {
        float acc = 0.f;
        #pragma unroll
        for (int e = 0; e < D_DIM; ++e) acc += Lr[e] * __shfl(Lr[e], f);
        if (lane < D_DIM) S_lds[lane][f] = acc;
    }
    __syncthreads();

    // c' = c - 0.5; Sc' ; c'Sc'
    float c[D_DIM];
    {
        const float4* cc = (const float4*)(centers + (size_t)j * D_DIM);
        #pragma unroll
        for (int q = 0; q < 4; ++q) {
            const float4 v = cc[q];
            c[q * 4 + 0] = v.x - 0.5f; c[q * 4 + 1] = v.y - 0.5f;
            c[q * 4 + 2] = v.z - 0.5f; c[q * 4 + 3] = v.w - 0.5f;
        }
    }
    if (lane < D_DIM) {
        float acc = 0.f;
        #pragma unroll
        for (int f = 0; f < D_DIM; ++f) acc += S_lds[lane][f] * c[f];
        Scp_lds[lane] = acc;
    }
    __syncthreads();
    float cSc = 0.f;
    #pragma unroll
    for (int d = 0; d < D_DIM; ++d) cSc += c[d] * Scp_lds[d];

    // sum |w| over 128 entries
    float wa = fabsf(weights[lane]) + fabsf(weights[lane + 64]);
    #pragma unroll
    for (int off = 32; off > 0; off >>= 1) wa += __shfl_xor(wa, off);
    const float lc = logf(fabsf(weights[j])) - logf(wa + 1e-30f) + logdet;

    float* constsG = ws + WS_CONST_F32_OFF;
    if (lane == 0) constsG[j] = (lc - 0.5f * cSc) * LOG2E;

    // A-frag writes: lanes 0..19 -> (t, hi); values scaled by LOG2E
    if (lane < 2 * KSTEPS) {
        const int t  = lane >> 1;
        const int hi = lane & 1;
        const int h  = j >> 6;
        const int mt = (j >> 5) & 1;
        half8 hv;
        for (int e = 0; e < 8; ++e) {
            const int s  = t * 8 + e;
            const int mm = TAB.m[s], a = TAB.a[s], b = TAB.b[s];
            float val;
            if (mm == 0) {
                const int d = hi ? ((a + 8) & 15) : a;
                const int f = hi ? ((b + 8) & 15) : b;
                val = (d == f) ? -0.5f * S_lds[d][d] : -S_lds[d][f];
            } else if (mm == 1) {
                const int d = a + 4 * hi, f = a + 8 + 4 * hi;
                val = -S_lds[d][f];
            } else if (mm == 2) {
                val = Scp_lds[a + 8 * hi];
            } else {
                val = 0.f;
            }
            hv[e] = (_Float16)(val * LOG2E);
        }
        char* dst = (char*)ws + ((((h * 2 + mt) * KSTEPS + t) * 64) + hi * 32 + (j & 31)) * 16;
        *(half8*)dst = hv;
    }
}

// ---------------------------------------------------------------------------
// Main: 2-wave blocks; wave w owns center-half w. Grid-stride over tiles with
// software prefetch of the next tile's points; exp2-domain logsumexp.
// ---------------------------------------------------------------------------
__global__ __launch_bounds__(128, 4) void gmm_main_kernel(
    const float* __restrict__ points,    // [N,16]
    const float* __restrict__ wsf,
    const float* __restrict__ thr,       // [1]
    float* __restrict__ out,             // [N]
    int ntiles)
{
    const int tid = threadIdx.x;
    const int w   = tid >> 6;            // center-half
    const int l   = tid & 63;
    const int col = l & 31;              // point within tile
    const bool hi = (l >> 5) != 0;

    // Preload A fragments (C-matrix, fp16) — loop-invariant
    half8 A[2][KSTEPS];
    {
        const char* wsb = (const char*)wsf;
        #pragma unroll
        for (int mt = 0; mt < 2; ++mt)
            #pragma unroll
            for (int t = 0; t < KSTEPS; ++t)
                A[mt][t] = *(const half8*)(wsb + ((((w * 2 + mt) * KSTEPS + t) * 64) + l) * 16);
    }

    // Per-lane consts for the 32 (mt,reg) accumulator rows (log2 domain)
    float cst[32];
    {
        const float* cstG = wsf + WS_CONST_F32_OFF;
        #pragma unroll
        for (int mt = 0; mt < 2; ++mt)
            #pragma unroll
            for (int rr = 0; rr < 16; ++rr)
                cst[mt * 16 + rr] =
                    cstG[w * 64 + mt * 32 + (rr & 3) + 8 * (rr >> 2) + 4 * (l >> 5)];
    }

    const float thrv = thr[0];
    __shared__ float lm[2][32], ls[2][32];

    const float4* pbase = (const float4*)points;
    int tile = blockIdx.x;
    float4 pf0, pf1, pf2, pf3;
    if (tile < ntiles) {
        const float4* px = pbase + ((size_t)tile * 32 + col) * 4;
        pf0 = px[0]; pf1 = px[1]; pf2 = px[2]; pf3 = px[3];
    }

    for (; tile < ntiles; tile += GRID_MAIN) {
        // z = x - 0.5 from prefetched regs
        float z[D_DIM];
        z[0]=pf0.x-0.5f; z[1]=pf0.y-0.5f; z[2]=pf0.z-0.5f; z[3]=pf0.w-0.5f;
        z[4]=pf1.x-0.5f; z[5]=pf1.y-0.5f; z[6]=pf1.z-0.5f; z[7]=pf1.w-0.5f;
        z[8]=pf2.x-0.5f; z[9]=pf2.y-0.5f; z[10]=pf2.z-0.5f; z[11]=pf2.w-0.5f;
        z[12]=pf3.x-0.5f; z[13]=pf3.y-0.5f; z[14]=pf3.z-0.5f; z[15]=pf3.w-0.5f;

        // sigma-select arrays (cndmask on lane-half, no divergence)
        float zs8[16], z4l[4], z4h[4];
        #pragma unroll
        for (int i = 0; i < 16; ++i) zs8[i] = hi ? z[(i + 8) & 15] : z[i];
        #pragma unroll
        for (int i = 0; i < 4; ++i) {
            z4l[i] = hi ? z[i + 4]  : z[i];
            z4h[i] = hi ? z[i + 12] : z[i + 8];
        }

        f32x16 acc0 = {0.f, 0.f, 0.f, 0.f, 0.f, 0.f, 0.f, 0.f,
                       0.f, 0.f, 0.f, 0.f, 0.f, 0.f, 0.f, 0.f};
        f32x16 acc1 = acc0;

        #pragma unroll
        for (int t = 0; t < KSTEPS; ++t) {
            half8 bf;
            #pragma unroll
            for (int e = 0; e < 8; ++e) {
                const int s  = t * 8 + e;
                const int mm = TAB.m[s], a = TAB.a[s], b = TAB.b[s];
                float p = (mm == 0) ? zs8[a] * zs8[b]
                        : (mm == 1) ? z4l[a] * z4h[a]
                        : (mm == 2) ? zs8[a]
                        : 0.f;
                bf[e] = (_Float16)p;
            }
            acc0 = __builtin_amdgcn_mfma_f32_32x32x16_f16(A[0][t], bf, acc0, 0, 0, 0);
            acc1 = __builtin_amdgcn_mfma_f32_32x32x16_f16(A[1][t], bf, acc1, 0, 0, 0);
        }

        // prefetch next tile's points (hides HBM latency under the epilogue)
        {
            const int nxt = tile + GRID_MAIN;
            if (nxt < ntiles) {
                const float4* px = pbase + ((size_t)nxt * 32 + col) * 4;
                pf0 = px[0]; pf1 = px[1]; pf2 = px[2]; pf3 = px[3];
            }
        }

        // epilogue (log2 domain): v = acc + const; max; sum 2^(v-max)
        float v[32];
        #pragma unroll
        for (int rr = 0; rr < 16; ++rr) {
            v[rr]      = acc0[rr] + cst[rr];
            v[16 + rr] = acc1[rr] + cst[16 + rr];
        }
        float tm[16];
        #pragma unroll
        for (int i = 0; i < 16; ++i) tm[i] = fmaxf(v[i], v[i + 16]);
        // max3-friendly reduce: 16 -> 6 -> 2 -> 1
        float r0 = fmaxf(fmaxf(tm[0], tm[1]), tm[2]);
        float r1 = fmaxf(fmaxf(tm[3], tm[4]), tm[5]);
        float r2 = fmaxf(fmaxf(tm[6], tm[7]), tm[8]);
        float r3 = fmaxf(fmaxf(tm[9], tm[10]), tm[11]);
        float r4 = fmaxf(fmaxf(tm[12], tm[13]), tm[14]);
        float ra = fmaxf(fmaxf(r0, r1), r2);
        float rb = fmaxf(fmaxf(r3, r4), tm[15]);
        const float mx = fmaxf(ra, rb);

        float s0 = 0.f, s1 = 0.f, s2 = 0.f, s3 = 0.f;
        #pragma unroll
        for (int i = 0; i < 32; i += 4) {
            s0 += __builtin_amdgcn_exp2f(v[i + 0] - mx);
            s1 += __builtin_amdgcn_exp2f(v[i + 1] - mx);
            s2 += __builtin_amdgcn_exp2f(v[i + 2] - mx);
            s3 += __builtin_amdgcn_exp2f(v[i + 3] - mx);
        }
        float ss = (s0 + s1) + (s2 + s3);

        const float om = __shfl_xor(mx, 32);
        const float os = __shfl_xor(ss, 32);
        const float M2 = fmaxf(mx, om);
        const float S2 = ss * __builtin_amdgcn_exp2f(mx - M2)
                       + os * __builtin_amdgcn_exp2f(om - M2);

        if (l < 32) { lm[w][l] = M2; ls[w][l] = S2; }
        __syncthreads();
        if (w == 0 && l < 32) {
            const float m0 = lm[0][l], m1 = lm[1][l];
            const float MM = fmaxf(m0, m1);
            const float SS = ls[0][l] * __builtin_amdgcn_exp2f(m0 - MM)
                           + ls[1][l] * __builtin_amdgcn_exp2f(m1 - MM);
            out[tile * 32 + l] = fmaf(LN2, MM + __builtin_amdgcn_logf(SS), -thrv);
        }
        __syncthreads();
    }
}

extern "C" void kernel_launch(void* const* d_in, const int* in_sizes, int n_in,
                              void* d_out, int out_size, void* d_ws, size_t ws_size,
                              hipStream_t stream) {
    const float* points  = (const float*)d_in[0];
    const float* centers = (const float*)d_in[1];
    const float* covs    = (const float*)d_in[2];
    const float* weights = (const float*)d_in[3];
    const float* thr     = (const float*)d_in[4];
    float* out = (float*)d_out;
    float* ws  = (float*)d_ws;

    const int n      = in_sizes[0] / D_DIM;   // 500000
    const int ntiles = n / 32;                // 15625 (exact)

    gmm_prep_kernel<<<M_CTR, 64, 0, stream>>>(centers, covs, weights, ws);
    gmm_main_kernel<<<GRID_MAIN, 128, 0, stream>>>(points, ws, thr, out, ntiles);
}

// Round 5
// 46.735 us; speedup vs baseline: 3.0706x; 3.0706x over previous
//
#include <hip/hip_runtime.h>
#include <math.h>

// N=500000 points, M=128 centers, D=16.
#define M_CTR 128
#define D_DIM 16
#define KSTEPS 10          // K = 160 = 10 x 16
#define NSLOT 80           // phi slots per lane-half (80 x 2 = 160 = K)
#define GRID_MAIN 4096
// ws layout: [0,40960) A-frags fp16 (40 frag-blocks x 1KB); [40960,41472) consts f32[128]
#define WS_CONST_F32_OFF 10240
#define LOG2E 1.4426950408889634f
#define LN2   0.6931471805599453f

typedef _Float16 half8 __attribute__((ext_vector_type(8)));
typedef float f32x16 __attribute__((ext_vector_type(16)));

// ---------------------------------------------------------------------------
// Slot table: maps frag slot s (= t*8+e, per lane-half) -> feature.
// Lane-half hi=0 takes (a,b) as-is; hi=1 applies sigma: +8 mod 16 (mode 0/2)
// or +4 (mode 1). modes: 0 = zs8[a]*zs8[b], 1 = z4l[a]*z4h[a], 2 = zs8[a], 3 = 0.
// ---------------------------------------------------------------------------
struct SlotTab { unsigned char a[NSLOT]; unsigned char b[NSLOT]; unsigned char m[NSLOT]; };
constexpr SlotTab make_tab() {
    SlotTab T{};
    int s = 0;
    for (int d = 0; d < 8; ++d) { T.a[s] = (unsigned char)d; T.b[s] = (unsigned char)d; T.m[s] = 0; ++s; }
    for (int d = 0; d < 8; ++d)
        for (int f = d + 1; f < 8; ++f) { T.a[s] = (unsigned char)d; T.b[s] = (unsigned char)f; T.m[s] = 0; ++s; }
    for (int d = 0; d < 8; ++d)
        for (int f2 = d + 1; f2 < 8; ++f2) { T.a[s] = (unsigned char)d; T.b[s] = (unsigned char)(f2 + 8); T.m[s] = 0; ++s; }
    for (int d = 0; d < 4; ++d) { T.a[s] = (unsigned char)d; T.b[s] = (unsigned char)(d + 8); T.m[s] = 1; ++s; }
    for (int d = 0; d < 8; ++d) { T.a[s] = (unsigned char)d; T.b[s] = 0; T.m[s] = 2; ++s; }
    for (; s < NSLOT; ++s) { T.a[s] = 0; T.b[s] = 0; T.m[s] = 3; }
    return T;
}
constexpr SlotTab TAB = make_tab();

// ---------------------------------------------------------------------------
// Prep: one 64-thread block per center j. All coefficients scaled by LOG2E
// so the main kernel works in the exp2/log2 domain.
// ---------------------------------------------------------------------------
__global__ __launch_bounds__(64) void gmm_prep_kernel(
    const float* __restrict__ centers,   // [M,16]
    const float* __restrict__ Lmat,      // [M,16,16]
    const float* __restrict__ weights,   // [M]
    float* __restrict__ ws)
{
    const int j    = blockIdx.x;
    const int lane = threadIdx.x;        // 0..63
    const int r    = lane & 15;

    __shared__ float S_lds[D_DIM][D_DIM + 1];
    __shared__ float Scp_lds[D_DIM];

    float Lr[D_DIM];
    {
        const float4* Lrow = (const float4*)(Lmat + (size_t)j * 256 + r * 16);
        #pragma unroll
        for (int q = 0; q < 4; ++q) {
            const float4 v = Lrow[q];
            Lr[q * 4 + 0] = v.x; Lr[q * 4 + 1] = v.y;
            Lr[q * 4 + 2] = v.z; Lr[q * 4 + 3] = v.w;
        }
    }

    // log|det L| via lane-parallel LU (L ~ 15I + 0.1*noise, diag dominant)
    float u[D_DIM];
    #pragma unroll
    for (int e = 0; e < D_DIM; ++e) u[e] = Lr[e];
    float logdet = 0.f;
    #pragma unroll
    for (int k = 0; k < D_DIM; ++k) {
        const float pk = __shfl(u[k], k);
        logdet += logf(fabsf(pk));
        const float f = u[k] * (1.0f / pk);
        #pragma unroll
        for (int c = k + 1; c < D_DIM; ++c) {
            const float rkc = __shfl(u[c], k);
            if (r > k) u[c] -= f * rkc;
        }
    }

    // S = L L^T
    #pragma unroll
    for (int f = 0; f < D_DIM; ++f) {
        float acc = 0.f;
        #pragma unroll
        for (int e = 0; e < D_DIM; ++e) acc += Lr[e] * __shfl(Lr[e], f);
        if (lane < D_DIM) S_lds[lane][f] = acc;
    }
    __syncthreads();

    // c' = c - 0.5; Sc' ; c'Sc'
    float c[D_DIM];
    {
        const float4* cc = (const float4*)(centers + (size_t)j * D_DIM);
        #pragma unroll
        for (int q = 0; q < 4; ++q) {
            const float4 v = cc[q];
            c[q * 4 + 0] = v.x - 0.5f; c[q * 4 + 1] = v.y - 0.5f;
            c[q * 4 + 2] = v.z - 0.5f; c[q * 4 + 3] = v.w - 0.5f;
        }
    }
    if (lane < D_DIM) {
        float acc = 0.f;
        #pragma unroll
        for (int f = 0; f < D_DIM; ++f) acc += S_lds[lane][f] * c[f];
        Scp_lds[lane] = acc;
    }
    __syncthreads();
    float cSc = 0.f;
    #pragma unroll
    for (int d = 0; d < D_DIM; ++d) cSc += c[d] * Scp_lds[d];

    // sum |w| over 128 entries
    float wa = fabsf(weights[lane]) + fabsf(weights[lane + 64]);
    #pragma unroll
    for (int off = 32; off > 0; off >>= 1) wa += __shfl_xor(wa, off);
    const float lc = logf(fabsf(weights[j])) - logf(wa + 1e-30f) + logdet;

    float* constsG = ws + WS_CONST_F32_OFF;
    if (lane == 0) constsG[j] = (lc - 0.5f * cSc) * LOG2E;

    // A-frag writes: lanes 0..19 -> (t, hi); values scaled by LOG2E
    if (lane < 2 * KSTEPS) {
        const int t  = lane >> 1;
        const int hi = lane & 1;
        const int h  = j >> 6;
        const int mt = (j >> 5) & 1;
        half8 hv;
        for (int e = 0; e < 8; ++e) {
            const int s  = t * 8 + e;
            const int mm = TAB.m[s], a = TAB.a[s], b = TAB.b[s];
            float val;
            if (mm == 0) {
                const int d = hi ? ((a + 8) & 15) : a;
                const int f = hi ? ((b + 8) & 15) : b;
                val = (d == f) ? -0.5f * S_lds[d][d] : -S_lds[d][f];
            } else if (mm == 1) {
                const int d = a + 4 * hi, f = a + 8 + 4 * hi;
                val = -S_lds[d][f];
            } else if (mm == 2) {
                val = Scp_lds[a + 8 * hi];
            } else {
                val = 0.f;
            }
            hv[e] = (_Float16)(val * LOG2E);
        }
        char* dst = (char*)ws + ((((h * 2 + mt) * KSTEPS + t) * 64) + hi * 32 + (j & 31)) * 16;
        *(half8*)dst = hv;
    }
}

// ---------------------------------------------------------------------------
// Main: 2-wave blocks; wave w owns center-half w. Grid-stride over tiles with
// software prefetch; exp2-domain logsumexp; parity-buffered wave merge
// (single __syncthreads per tile).
// ---------------------------------------------------------------------------
__global__ __launch_bounds__(128, 2) void gmm_main_kernel(
    const float* __restrict__ points,    // [N,16]
    const float* __restrict__ wsf,
    const float* __restrict__ thr,       // [1]
    float* __restrict__ out,             // [N]
    int ntiles)
{
    const int tid = threadIdx.x;
    const int w   = tid >> 6;            // center-half
    const int l   = tid & 63;
    const int col = l & 31;              // point within tile
    const bool hi = (l >> 5) != 0;

    // Preload A fragments (C-matrix, fp16) — loop-invariant
    half8 A[2][KSTEPS];
    {
        const char* wsb = (const char*)wsf;
        #pragma unroll
        for (int mt = 0; mt < 2; ++mt)
            #pragma unroll
            for (int t = 0; t < KSTEPS; ++t)
                A[mt][t] = *(const half8*)(wsb + ((((w * 2 + mt) * KSTEPS + t) * 64) + l) * 16);
    }

    // Per-lane consts for the 32 (mt,reg) accumulator rows (log2 domain)
    float cst[32];
    {
        const float* cstG = wsf + WS_CONST_F32_OFF;
        #pragma unroll
        for (int mt = 0; mt < 2; ++mt)
            #pragma unroll
            for (int rr = 0; rr < 16; ++rr)
                cst[mt * 16 + rr] =
                    cstG[w * 64 + mt * 32 + (rr & 3) + 8 * (rr >> 2) + 4 * (l >> 5)];
    }

    const float thrv = thr[0];
    __shared__ float lm[2][2][32], ls[2][2][32];   // [parity][wave][point]

    const float4* pbase = (const float4*)points;
    int tile = blockIdx.x;
    int par  = 0;
    float4 pf0, pf1, pf2, pf3;
    if (tile < ntiles) {
        const float4* px = pbase + ((size_t)tile * 32 + col) * 4;
        pf0 = px[0]; pf1 = px[1]; pf2 = px[2]; pf3 = px[3];
    }

    for (; tile < ntiles; tile += GRID_MAIN, par ^= 1) {
        // z = x - 0.5 from prefetched regs
        float z[D_DIM];
        z[0]=pf0.x-0.5f; z[1]=pf0.y-0.5f; z[2]=pf0.z-0.5f; z[3]=pf0.w-0.5f;
        z[4]=pf1.x-0.5f; z[5]=pf1.y-0.5f; z[6]=pf1.z-0.5f; z[7]=pf1.w-0.5f;
        z[8]=pf2.x-0.5f; z[9]=pf2.y-0.5f; z[10]=pf2.z-0.5f; z[11]=pf2.w-0.5f;
        z[12]=pf3.x-0.5f; z[13]=pf3.y-0.5f; z[14]=pf3.z-0.5f; z[15]=pf3.w-0.5f;

        // sigma-select arrays (cndmask on lane-half, no divergence)
        float zs8[16], z4l[4], z4h[4];
        #pragma unroll
        for (int i = 0; i < 16; ++i) zs8[i] = hi ? z[(i + 8) & 15] : z[i];
        #pragma unroll
        for (int i = 0; i < 4; ++i) {
            z4l[i] = hi ? z[i + 4]  : z[i];
            z4h[i] = hi ? z[i + 12] : z[i + 8];
        }

        f32x16 acc0 = {0.f, 0.f, 0.f, 0.f, 0.f, 0.f, 0.f, 0.f,
                       0.f, 0.f, 0.f, 0.f, 0.f, 0.f, 0.f, 0.f};
        f32x16 acc1 = acc0;

        #pragma unroll
        for (int t = 0; t < KSTEPS; ++t) {
            half8 bf;
            #pragma unroll
            for (int e = 0; e < 8; ++e) {
                const int s  = t * 8 + e;
                const int mm = TAB.m[s], a = TAB.a[s], b = TAB.b[s];
                float p = (mm == 0) ? zs8[a] * zs8[b]
                        : (mm == 1) ? z4l[a] * z4h[a]
                        : (mm == 2) ? zs8[a]
                        : 0.f;
                bf[e] = (_Float16)p;
            }
            acc0 = __builtin_amdgcn_mfma_f32_32x32x16_f16(A[0][t], bf, acc0, 0, 0, 0);
            acc1 = __builtin_amdgcn_mfma_f32_32x32x16_f16(A[1][t], bf, acc1, 0, 0, 0);
        }

        // prefetch next tile's points (hides HBM latency under the epilogue)
        {
            const int nxt = tile + GRID_MAIN;
            if (nxt < ntiles) {
                const float4* px = pbase + ((size_t)nxt * 32 + col) * 4;
                pf0 = px[0]; pf1 = px[1]; pf2 = px[2]; pf3 = px[3];
            }
        }

        // epilogue (log2 domain)
        float v[32];
        #pragma unroll
        for (int rr = 0; rr < 16; ++rr) {
            v[rr]      = acc0[rr] + cst[rr];
            v[16 + rr] = acc1[rr] + cst[16 + rr];
        }
        float tm[16];
        #pragma unroll
        for (int i = 0; i < 16; ++i) tm[i] = fmaxf(v[i], v[i + 16]);
        float r0 = fmaxf(fmaxf(tm[0], tm[1]), tm[2]);
        float r1 = fmaxf(fmaxf(tm[3], tm[4]), tm[5]);
        float r2 = fmaxf(fmaxf(tm[6], tm[7]), tm[8]);
        float r3 = fmaxf(fmaxf(tm[9], tm[10]), tm[11]);
        float r4 = fmaxf(fmaxf(tm[12], tm[13]), tm[14]);
        float ra = fmaxf(fmaxf(r0, r1), r2);
        float rb = fmaxf(fmaxf(r3, r4), tm[15]);
        const float mx = fmaxf(ra, rb);

        float s0 = 0.f, s1 = 0.f, s2 = 0.f, s3 = 0.f;
        #pragma unroll
        for (int i = 0; i < 32; i += 4) {
            s0 += __builtin_amdgcn_exp2f(v[i + 0] - mx);
            s1 += __builtin_amdgcn_exp2f(v[i + 1] - mx);
            s2 += __builtin_amdgcn_exp2f(v[i + 2] - mx);
            s3 += __builtin_amdgcn_exp2f(v[i + 3] - mx);
        }
        float ss = (s0 + s1) + (s2 + s3);

        const float om = __shfl_xor(mx, 32);
        const float os = __shfl_xor(ss, 32);
        const float M2 = fmaxf(mx, om);
        const float S2 = ss * __builtin_amdgcn_exp2f(mx - M2)
                       + os * __builtin_amdgcn_exp2f(om - M2);

        if (l < 32) { lm[par][w][l] = M2; ls[par][w][l] = S2; }
        __syncthreads();
        if (w == 0 && l < 32) {
            const float m0 = lm[par][0][l], m1 = lm[par][1][l];
            const float MM = fmaxf(m0, m1);
            const float SS = ls[par][0][l] * __builtin_amdgcn_exp2f(m0 - MM)
                           + ls[par][1][l] * __builtin_amdgcn_exp2f(m1 - MM);
            out[tile * 32 + l] = fmaf(LN2, MM + __builtin_amdgcn_logf(SS), -thrv);
        }
        // no second barrier: parity buffers are only rewritten 2 iterations
        // later, with a barrier in between.
    }
}

extern "C" void kernel_launch(void* const* d_in, const int* in_sizes, int n_in,
                              void* d_out, int out_size, void* d_ws, size_t ws_size,
                              hipStream_t stream) {
    const float* points  = (const float*)d_in[0];
    const float* centers = (const float*)d_in[1];
    const float* covs    = (const float*)d_in[2];
    const float* weights = (const float*)d_in[3];
    const float* thr     = (const float*)d_in[4];
    float* out = (float*)d_out;
    float* ws  = (float*)d_ws;

    const int n      = in_sizes[0] / D_DIM;   // 500000
    const int ntiles = n / 32;                // 15625 (exact)

    gmm_prep_kernel<<<M_CTR, 64, 0, stream>>>(centers, covs, weights, ws);
    gmm_main_kernel<<<GRID_MAIN, 128, 0, stream>>>(points, ws, thr, out, ntiles);
}

// Round 7
// 45.505 us; speedup vs baseline: 3.1535x; 1.0270x over previous
//
#include <hip/hip_runtime.h>
#include <math.h>

// N=500000 points, M=128 centers, D=16.
#define M_CTR 128
#define D_DIM 16
#define KSTEPS 10          // K = 160 = 10 x 16
#define NSLOT 80           // phi slots per lane-half (80 x 2 = 160 = K)
#define GRID_MAIN 1024     // 256-thr blocks, 4 independent waves each
#define LOG2E 1.4426950408889634f
#define LN2   0.6931471805599453f

typedef _Float16 half8  __attribute__((ext_vector_type(8)));
typedef __fp16   fp16x2 __attribute__((ext_vector_type(2)));
typedef float   f32x16  __attribute__((ext_vector_type(16)));

// ---------------------------------------------------------------------------
// Slot table: maps frag slot s (= t*8+e, per lane-half) -> feature.
// hi=0 takes (a,b) as-is; hi=1 applies sigma: +8 mod 16 (mode 0/2) or +4
// (mode 1). modes: 0 = zs8[a]*zs8[b], 1 = z4l[a]*z4h[a], 2 = zs8[a],
// 3 = pad. Slot 76 (first pad) carries phi=1.0 and A=const_j/2 per half,
// folding the per-center constant into the GEMM.
// ---------------------------------------------------------------------------
struct SlotTab { unsigned char a[NSLOT]; unsigned char b[NSLOT]; unsigned char m[NSLOT]; };
constexpr SlotTab make_tab() {
    SlotTab T{};
    int s = 0;
    for (int d = 0; d < 8; ++d) { T.a[s] = (unsigned char)d; T.b[s] = (unsigned char)d; T.m[s] = 0; ++s; }
    for (int d = 0; d < 8; ++d)
        for (int f = d + 1; f < 8; ++f) { T.a[s] = (unsigned char)d; T.b[s] = (unsigned char)f; T.m[s] = 0; ++s; }
    for (int d = 0; d < 8; ++d)
        for (int f2 = d + 1; f2 < 8; ++f2) { T.a[s] = (unsigned char)d; T.b[s] = (unsigned char)(f2 + 8); T.m[s] = 0; ++s; }
    for (int d = 0; d < 4; ++d) { T.a[s] = (unsigned char)d; T.b[s] = (unsigned char)(d + 8); T.m[s] = 1; ++s; }
    for (int d = 0; d < 8; ++d) { T.a[s] = (unsigned char)d; T.b[s] = 0; T.m[s] = 2; ++s; }
    for (; s < NSLOT; ++s) { T.a[s] = 0; T.b[s] = 0; T.m[s] = 3; }
    return T;
}
constexpr SlotTab TAB = make_tab();

// ---------------------------------------------------------------------------
// Prep: one 64-thread block per center j. Coefficients scaled by LOG2E
// (exp2/log2 domain). A-frag layout: frag-block fb = (j>>5)*KSTEPS + t,
// element (fb*64 + lane)*16B; lane l holds rows j&31, k = 16t + 8*(l>>5)+e.
// ---------------------------------------------------------------------------
__global__ __launch_bounds__(64) void gmm_prep_kernel(
    const float* __restrict__ centers,   // [M,16]
    const float* __restrict__ Lmat,      // [M,16,16]
    const float* __restrict__ weights,   // [M]
    float* __restrict__ ws)
{
    const int j    = blockIdx.x;
    const int lane = threadIdx.x;        // 0..63
    const int r    = lane & 15;

    __shared__ float S_lds[D_DIM][D_DIM + 1];
    __shared__ float Scp_lds[D_DIM];

    float Lr[D_DIM];
    {
        const float4* Lrow = (const float4*)(Lmat + (size_t)j * 256 + r * 16);
        #pragma unroll
        for (int q = 0; q < 4; ++q) {
            const float4 v = Lrow[q];
            Lr[q * 4 + 0] = v.x; Lr[q * 4 + 1] = v.y;
            Lr[q * 4 + 2] = v.z; Lr[q * 4 + 3] = v.w;
        }
    }

    // log|det L| via lane-parallel LU (L ~ 15I + 0.1*noise, diag dominant)
    float u[D_DIM];
    #pragma unroll
    for (int e = 0; e < D_DIM; ++e) u[e] = Lr[e];
    float logdet = 0.f;
    #pragma unroll
    for (int k = 0; k < D_DIM; ++k) {
        const float pk = __shfl(u[k], k);
        logdet += logf(fabsf(pk));
        const float f = u[k] * (1.0f / pk);
        #pragma unroll
        for (int c = k + 1; c < D_DIM; ++c) {
            const float rkc = __shfl(u[c], k);
            if (r > k) u[c] -= f * rkc;
        }
    }

    // S = L L^T
    #pragma unroll
    for (int f = 0; f < D_DIM; ++f) {
        float acc = 0.f;
        #pragma unroll
        for (int e = 0; e < D_DIM; ++e) acc += Lr[e] * __shfl(Lr[e], f);
        if (lane < D_DIM) S_lds[lane][f] = acc;
    }
    __syncthreads();

    // c' = c - 0.5; Sc' ; c'Sc'
    float c[D_DIM];
    {
        const float4* cc = (const float4*)(centers + (size_t)j * D_DIM);
        #pragma unroll
        for (int q = 0; q < 4; ++q) {
            const float4 v = cc[q];
            c[q * 4 + 0] = v.x - 0.5f; c[q * 4 + 1] = v.y - 0.5f;
            c[q * 4 + 2] = v.z - 0.5f; c[q * 4 + 3] = v.w - 0.5f;
        }
    }
    if (lane < D_DIM) {
        float acc = 0.f;
        #pragma unroll
        for (int f = 0; f < D_DIM; ++f) acc += S_lds[lane][f] * c[f];
        Scp_lds[lane] = acc;
    }
    __syncthreads();
    float cSc = 0.f;
    #pragma unroll
    for (int d = 0; d < D_DIM; ++d) cSc += c[d] * Scp_lds[d];

    // sum |w| over 128 entries
    float wa = fabsf(weights[lane]) + fabsf(weights[lane + 64]);
    #pragma unroll
    for (int off = 32; off > 0; off >>= 1) wa += __shfl_xor(wa, off);
    const float lc = logf(fabsf(weights[j])) - logf(wa + 1e-30f) + logdet;
    const float cst_half = (lc - 0.5f * cSc) * 0.5f;   // per-half const (pre-LOG2E)

    // A-frag writes: lanes 0..19 -> (t, hi)
    if (lane < 2 * KSTEPS) {
        const int t  = lane >> 1;
        const int hi = lane & 1;
        const int mt = j >> 5;           // 0..3
        half8 hv;
        for (int e = 0; e < 8; ++e) {
            const int s  = t * 8 + e;
            const int mm = TAB.m[s], a = TAB.a[s], b = TAB.b[s];
            float val;
            if (mm == 0) {
                const int d = hi ? ((a + 8) & 15) : a;
                const int f = hi ? ((b + 8) & 15) : b;
                val = (d == f) ? -0.5f * S_lds[d][d] : -S_lds[d][f];
            } else if (mm == 1) {
                const int d = a + 4 * hi, f = a + 8 + 4 * hi;
                val = -S_lds[d][f];
            } else if (mm == 2) {
                val = Scp_lds[a + 8 * hi];
            } else {
                val = (s == 76) ? cst_half : 0.f;   // const folded into GEMM
            }
            hv[e] = (_Float16)(val * LOG2E);
        }
        char* dst = (char*)ws + (((mt * KSTEPS + t) * 64) + hi * 32 + (j & 31)) * 16;
        *(half8*)dst = hv;
    }
}

// ---------------------------------------------------------------------------
// Main: 256-thr blocks, 4 INDEPENDENT waves (no per-tile barrier). A-frags
// (all 128 centers, 40KB) staged once in LDS; each wave grid-strides over
// whole 32-point tiles, 4 MFMA chains (one per center group), full
// logsumexp in-wave (shfl_xor(32) half-merge only).
// ---------------------------------------------------------------------------
__global__ __launch_bounds__(256) void gmm_main_kernel(
    const float* __restrict__ points,    // [N,16]
    const float* __restrict__ wsf,       // A-frags (40KB)
    const float* __restrict__ thr,       // [1]
    float* __restrict__ out,             // [N]
    int ntiles)
{
    __shared__ float4 A_lds4[2560];      // 40960 B

    const int tid = threadIdx.x;
    const int w   = tid >> 6;
    const int l   = tid & 63;
    const int col = l & 31;
    const bool hi = (l >> 5) != 0;

    // cooperative A fill: 2560 float4 / 256 threads = 10 each
    {
        const float4* src = (const float4*)wsf;
        #pragma unroll
        for (int i = 0; i < 10; ++i)
            A_lds4[i * 256 + tid] = src[i * 256 + tid];
    }
    __syncthreads();                     // only barrier in the kernel

    const half8* Ah = (const half8*)A_lds4 + l;   // + (mt*10+t)*64 via imm offset
    const float thrv = thr[0];
    const float4* pbase = (const float4*)points;

    const int wid    = blockIdx.x * 4 + w;
    const int stride = GRID_MAIN * 4;

    int tile = wid;
    float4 pf0, pf1, pf2, pf3;
    if (tile < ntiles) {
        const float4* px = pbase + ((size_t)tile * 32 + col) * 4;
        pf0 = px[0]; pf1 = px[1]; pf2 = px[2]; pf3 = px[3];
    }

    for (; tile < ntiles; tile += stride) {
        float z[D_DIM];
        z[0]=pf0.x-0.5f; z[1]=pf0.y-0.5f; z[2]=pf0.z-0.5f; z[3]=pf0.w-0.5f;
        z[4]=pf1.x-0.5f; z[5]=pf1.y-0.5f; z[6]=pf1.z-0.5f; z[7]=pf1.w-0.5f;
        z[8]=pf2.x-0.5f; z[9]=pf2.y-0.5f; z[10]=pf2.z-0.5f; z[11]=pf2.w-0.5f;
        z[12]=pf3.x-0.5f; z[13]=pf3.y-0.5f; z[14]=pf3.z-0.5f; z[15]=pf3.w-0.5f;

        float zs8[16], z4l[4], z4h[4];
        #pragma unroll
        for (int i = 0; i < 16; ++i) zs8[i] = hi ? z[(i + 8) & 15] : z[i];
        #pragma unroll
        for (int i = 0; i < 4; ++i) {
            z4l[i] = hi ? z[i + 4]  : z[i];
            z4h[i] = hi ? z[i + 12] : z[i + 8];
        }

        f32x16 acc0 = {0.f,0.f,0.f,0.f,0.f,0.f,0.f,0.f,0.f,0.f,0.f,0.f,0.f,0.f,0.f,0.f};
        f32x16 acc1 = acc0, acc2 = acc0, acc3 = acc0;

        #pragma unroll
        for (int t = 0; t < KSTEPS; ++t) {
            float pv[8];
            #pragma unroll
            for (int e = 0; e < 8; ++e) {
                const int s  = t * 8 + e;
                const int mm = TAB.m[s], a = TAB.a[s], b = TAB.b[s];
                pv[e] = (mm == 0) ? zs8[a] * zs8[b]
                      : (mm == 1) ? z4l[a] * z4h[a]
                      : (mm == 2) ? zs8[a]
                      : ((s == 76) ? 1.0f : 0.0f);
            }
            union { half8 h8; fp16x2 h2[4]; } u;
            u.h2[0] = __builtin_amdgcn_cvt_pkrtz(pv[0], pv[1]);
            u.h2[1] = __builtin_amdgcn_cvt_pkrtz(pv[2], pv[3]);
            u.h2[2] = __builtin_amdgcn_cvt_pkrtz(pv[4], pv[5]);
            u.h2[3] = __builtin_amdgcn_cvt_pkrtz(pv[6], pv[7]);
            const half8 bf = u.h8;

            const half8 a0 = Ah[(0 * KSTEPS + t) * 64];
            const half8 a1 = Ah[(1 * KSTEPS + t) * 64];
            const half8 a2 = Ah[(2 * KSTEPS + t) * 64];
            const half8 a3 = Ah[(3 * KSTEPS + t) * 64];
            acc0 = __builtin_amdgcn_mfma_f32_32x32x16_f16(a0, bf, acc0, 0, 0, 0);
            acc1 = __builtin_amdgcn_mfma_f32_32x32x16_f16(a1, bf, acc1, 0, 0, 0);
            acc2 = __builtin_amdgcn_mfma_f32_32x32x16_f16(a2, bf, acc2, 0, 0, 0);
            acc3 = __builtin_amdgcn_mfma_f32_32x32x16_f16(a3, bf, acc3, 0, 0, 0);
        }

        // prefetch next tile's points (hides HBM latency under the epilogue)
        {
            const int nxt = tile + stride;
            if (nxt < ntiles) {
                const float4* px = pbase + ((size_t)nxt * 32 + col) * 4;
                pf0 = px[0]; pf1 = px[1]; pf2 = px[2]; pf3 = px[3];
            }
        }

        // epilogue (log2 domain): max over this lane's 64 center-values
        float t0[8];
        #pragma unroll
        for (int i = 0; i < 8; ++i)
            t0[i] = fmaxf(fmaxf(acc0[i], acc0[i + 8]), fmaxf(acc1[i], acc1[i + 8]));
        #pragma unroll
        for (int i = 0; i < 8; ++i)
            t0[i] = fmaxf(t0[i], fmaxf(fmaxf(acc2[i], acc2[i + 8]), fmaxf(acc3[i], acc3[i + 8])));
        float m0 = fmaxf(fmaxf(t0[0], t0[1]), fmaxf(t0[2], t0[3]));
        float m1 = fmaxf(fmaxf(t0[4], t0[5]), fmaxf(t0[6], t0[7]));
        const float mx = fmaxf(m0, m1);

        float s0 = 0.f, s1 = 0.f, s2 = 0.f, s3 = 0.f;
        #pragma unroll
        for (int rr = 0; rr < 16; ++rr) {
            s0 += __builtin_amdgcn_exp2f(acc0[rr] - mx);
            s1 += __builtin_amdgcn_exp2f(acc1[rr] - mx);
            s2 += __builtin_amdgcn_exp2f(acc2[rr] - mx);
            s3 += __builtin_amdgcn_exp2f(acc3[rr] - mx);
        }
        float ss = (s0 + s1) + (s2 + s3);

        // merge the two lane-halves (complementary rows, same point col)
        const float om = __shfl_xor(mx, 32);
        const float os = __shfl_xor(ss, 32);
        const float M2 = fmaxf(mx, om);
        const float S2 = ss * __builtin_amdgcn_exp2f(mx - M2)
                       + os * __builtin_amdgcn_exp2f(om - M2);

        if (l < 32)
            out[tile * 32 + l] = fmaf(LN2, M2 + __builtin_amdgcn_logf(S2), -thrv);
    }
}

extern "C" void kernel_launch(void* const* d_in, const int* in_sizes, int n_in,
                              void* d_out, int out_size, void* d_ws, size_t ws_size,
                              hipStream_t stream) {
    const float* points  = (const float*)d_in[0];
    const float* centers = (const float*)d_in[1];
    const float* covs    = (const float*)d_in[2];
    const float* weights = (const float*)d_in[3];
    const float* thr     = (const float*)d_in[4];
    float* out = (float*)d_out;
    float* ws  = (float*)d_ws;

    const int n      = in_sizes[0] / D_DIM;   // 500000
    const int ntiles = n / 32;                // 15625 (exact)

    gmm_prep_kernel<<<M_CTR, 64, 0, stream>>>(centers, covs, weights, ws);
    gmm_main_kernel<<<GRID_MAIN, 256, 0, stream>>>(points, ws, thr, out, ntiles);
}

// Round 8
// 42.727 us; speedup vs baseline: 3.3586x; 1.0650x over previous
//
#include <hip/hip_runtime.h>
#include <math.h>

// N=500000 points, M=128 centers, D=16.
#define M_CTR 128
#define D_DIM 16
#define KSTEPS 10          // K = 160 = 10 x 16
#define NSLOT 80           // phi slots per lane-half (80 x 2 = 160 = K)
#define GRID_MAIN 512      // 256-thr blocks; ~2 blocks/CU resident, single pass
#define LOG2E 1.4426950408889634f
#define LN2   0.6931471805599453f

typedef _Float16 half8  __attribute__((ext_vector_type(8)));
typedef __fp16   fp16x2 __attribute__((ext_vector_type(2)));
typedef float   f32x16  __attribute__((ext_vector_type(16)));

// ---------------------------------------------------------------------------
// Slot table: maps frag slot s (= t*8+e, per lane-half) -> feature.
// hi=0 takes (a,b) as-is; hi=1 applies sigma: +8 mod 16 (mode 0/2) or +4
// (mode 1). modes: 0 = zs[a]*zs[b], 1 = zl[a]*zh[a], 2 = zs[a], 3 = pad.
// Slot 76 carries phi=1.0 with A=const_j/2 per half (const folded into GEMM).
// ---------------------------------------------------------------------------
struct SlotTab { unsigned char a[NSLOT]; unsigned char b[NSLOT]; unsigned char m[NSLOT]; };
constexpr SlotTab make_tab() {
    SlotTab T{};
    int s = 0;
    for (int d = 0; d < 8; ++d) { T.a[s] = (unsigned char)d; T.b[s] = (unsigned char)d; T.m[s] = 0; ++s; }
    for (int d = 0; d < 8; ++d)
        for (int f = d + 1; f < 8; ++f) { T.a[s] = (unsigned char)d; T.b[s] = (unsigned char)f; T.m[s] = 0; ++s; }
    for (int d = 0; d < 8; ++d)
        for (int f2 = d + 1; f2 < 8; ++f2) { T.a[s] = (unsigned char)d; T.b[s] = (unsigned char)(f2 + 8); T.m[s] = 0; ++s; }
    for (int d = 0; d < 4; ++d) { T.a[s] = (unsigned char)d; T.b[s] = (unsigned char)(d + 8); T.m[s] = 1; ++s; }
    for (int d = 0; d < 8; ++d) { T.a[s] = (unsigned char)d; T.b[s] = 0; T.m[s] = 2; ++s; }
    for (; s < NSLOT; ++s) { T.a[s] = 0; T.b[s] = 0; T.m[s] = 3; }
    return T;
}
constexpr SlotTab TAB = make_tab();

// ---------------------------------------------------------------------------
// Prep: one 64-thread block per center j. Coefficients scaled by LOG2E
// (exp2/log2 domain). A-frag layout: frag-block fb = (j>>5)*KSTEPS + t,
// element (fb*64 + lane)*16B; lane l holds rows j&31, k = 16t + 8*(l>>5)+e.
// ---------------------------------------------------------------------------
__global__ __launch_bounds__(64) void gmm_prep_kernel(
    const float* __restrict__ centers,   // [M,16]
    const float* __restrict__ Lmat,      // [M,16,16]
    const float* __restrict__ weights,   // [M]
    float* __restrict__ ws)
{
    const int j    = blockIdx.x;
    const int lane = threadIdx.x;        // 0..63
    const int r    = lane & 15;

    __shared__ float S_lds[D_DIM][D_DIM + 1];
    __shared__ float Scp_lds[D_DIM];

    float Lr[D_DIM];
    {
        const float4* Lrow = (const float4*)(Lmat + (size_t)j * 256 + r * 16);
        #pragma unroll
        for (int q = 0; q < 4; ++q) {
            const float4 v = Lrow[q];
            Lr[q * 4 + 0] = v.x; Lr[q * 4 + 1] = v.y;
            Lr[q * 4 + 2] = v.z; Lr[q * 4 + 3] = v.w;
        }
    }

    // log|det L| via lane-parallel LU (L ~ 15I + 0.1*noise, diag dominant)
    float u[D_DIM];
    #pragma unroll
    for (int e = 0; e < D_DIM; ++e) u[e] = Lr[e];
    float logdet = 0.f;
    #pragma unroll
    for (int k = 0; k < D_DIM; ++k) {
        const float pk = __shfl(u[k], k);
        logdet += logf(fabsf(pk));
        const float f = u[k] * (1.0f / pk);
        #pragma unroll
        for (int c = k + 1; c < D_DIM; ++c) {
            const float rkc = __shfl(u[c], k);
            if (r > k) u[c] -= f * rkc;
        }
    }

    // S = L L^T
    #pragma unroll
    for (int f = 0; f < D_DIM; ++f) {
        float acc = 0.f;
        #pragma unroll
        for (int e = 0; e < D_DIM; ++e) acc += Lr[e] * __shfl(Lr[e], f);
        if (lane < D_DIM) S_lds[lane][f] = acc;
    }
    __syncthreads();

    // c' = c - 0.5; Sc' ; c'Sc'
    float c[D_DIM];
    {
        const float4* cc = (const float4*)(centers + (size_t)j * D_DIM);
        #pragma unroll
        for (int q = 0; q < 4; ++q) {
            const float4 v = cc[q];
            c[q * 4 + 0] = v.x - 0.5f; c[q * 4 + 1] = v.y - 0.5f;
            c[q * 4 + 2] = v.z - 0.5f; c[q * 4 + 3] = v.w - 0.5f;
        }
    }
    if (lane < D_DIM) {
        float acc = 0.f;
        #pragma unroll
        for (int f = 0; f < D_DIM; ++f) acc += S_lds[lane][f] * c[f];
        Scp_lds[lane] = acc;
    }
    __syncthreads();
    float cSc = 0.f;
    #pragma unroll
    for (int d = 0; d < D_DIM; ++d) cSc += c[d] * Scp_lds[d];

    // sum |w| over 128 entries
    float wa = fabsf(weights[lane]) + fabsf(weights[lane + 64]);
    #pragma unroll
    for (int off = 32; off > 0; off >>= 1) wa += __shfl_xor(wa, off);
    const float lc = logf(fabsf(weights[j])) - logf(wa + 1e-30f) + logdet;
    const float cst_half = (lc - 0.5f * cSc) * 0.5f;   // per-half const (pre-LOG2E)

    // A-frag writes: lanes 0..19 -> (t, hi)
    if (lane < 2 * KSTEPS) {
        const int t  = lane >> 1;
        const int hi = lane & 1;
        const int mt = j >> 5;           // 0..3
        half8 hv;
        for (int e = 0; e < 8; ++e) {
            const int s  = t * 8 + e;
            const int mm = TAB.m[s], a = TAB.a[s], b = TAB.b[s];
            float val;
            if (mm == 0) {
                const int d = hi ? ((a + 8) & 15) : a;
                const int f = hi ? ((b + 8) & 15) : b;
                val = (d == f) ? -0.5f * S_lds[d][d] : -S_lds[d][f];
            } else if (mm == 1) {
                const int d = a + 4 * hi, f = a + 8 + 4 * hi;
                val = -S_lds[d][f];
            } else if (mm == 2) {
                val = Scp_lds[a + 8 * hi];
            } else {
                val = (s == 76) ? cst_half : 0.f;   // const folded into GEMM
            }
            hv[e] = (_Float16)(val * LOG2E);
        }
        char* dst = (char*)ws + (((mt * KSTEPS + t) * 64) + hi * 32 + (j & 31)) * 16;
        *(half8*)dst = hv;
    }
}

// build one B fragment for K-step t from sigma-selected feature regs
#define MAKE_BF(BF, ZS, ZL, ZH)                                             \
    do {                                                                    \
        float pv[8];                                                        \
        _Pragma("unroll")                                                   \
        for (int e = 0; e < 8; ++e) {                                       \
            const int s  = t * 8 + e;                                       \
            const int mm = TAB.m[s], a = TAB.a[s], b = TAB.b[s];            \
            pv[e] = (mm == 0) ? ZS[a] * ZS[b]                               \
                  : (mm == 1) ? ZL[a] * ZH[a]                               \
                  : (mm == 2) ? ZS[a]                                       \
                  : ((s == 76) ? 1.0f : 0.0f);                              \
        }                                                                   \
        union { half8 h8; fp16x2 h2[4]; } u_;                               \
        u_.h2[0] = __builtin_amdgcn_cvt_pkrtz(pv[0], pv[1]);                \
        u_.h2[1] = __builtin_amdgcn_cvt_pkrtz(pv[2], pv[3]);                \
        u_.h2[2] = __builtin_amdgcn_cvt_pkrtz(pv[4], pv[5]);                \
        u_.h2[3] = __builtin_amdgcn_cvt_pkrtz(pv[6], pv[7]);                \
        BF = u_.h8;                                                         \
    } while (0)

// epilogue: logsumexp over one tile's 4 accumulators -> per-point result
#define EPILOGUE(ACC0, ACC1, ACC2, ACC3, TIDX, VALID)                       \
    do {                                                                    \
        float t0[8];                                                        \
        _Pragma("unroll")                                                   \
        for (int i = 0; i < 8; ++i)                                         \
            t0[i] = fmaxf(fmaxf(ACC0[i], ACC0[i + 8]),                      \
                          fmaxf(ACC1[i], ACC1[i + 8]));                     \
        _Pragma("unroll")                                                   \
        for (int i = 0; i < 8; ++i)                                         \
            t0[i] = fmaxf(t0[i], fmaxf(fmaxf(ACC2[i], ACC2[i + 8]),         \
                                       fmaxf(ACC3[i], ACC3[i + 8])));       \
        float m0_ = fmaxf(fmaxf(t0[0], t0[1]), fmaxf(t0[2], t0[3]));        \
        float m1_ = fmaxf(fmaxf(t0[4], t0[5]), fmaxf(t0[6], t0[7]));        \
        const float mx = fmaxf(m0_, m1_);                                   \
        float s0 = 0.f, s1 = 0.f, s2 = 0.f, s3 = 0.f;                       \
        _Pragma("unroll")                                                   \
        for (int rr = 0; rr < 16; ++rr) {                                   \
            s0 += __builtin_amdgcn_exp2f(ACC0[rr] - mx);                    \
            s1 += __builtin_amdgcn_exp2f(ACC1[rr] - mx);                    \
            s2 += __builtin_amdgcn_exp2f(ACC2[rr] - mx);                    \
            s3 += __builtin_amdgcn_exp2f(ACC3[rr] - mx);                    \
        }                                                                   \
        float ss = (s0 + s1) + (s2 + s3);                                   \
        const float om = __shfl_xor(mx, 32);                                \
        const float os = __shfl_xor(ss, 32);                                \
        const float M2 = fmaxf(mx, om);                                     \
        const float S2 = ss * __builtin_amdgcn_exp2f(mx - M2)               \
                       + os * __builtin_amdgcn_exp2f(om - M2);              \
        if ((VALID) && l < 32)                                              \
            out[(TIDX) * 32 + l] =                                          \
                fmaf(LN2, M2 + __builtin_amdgcn_logf(S2), -thrv);           \
    } while (0)

// ---------------------------------------------------------------------------
// Main: 256-thr blocks, 4 independent waves. A-frags (128 centers, 40KB)
// staged once in LDS. Each wave-iteration processes TWO adjacent 32-point
// tiles: 8 interleaved MFMA chains share the same A ds_reads (half the LDS
// traffic per point) and the two epilogues provide cross-chain ILP.
// ---------------------------------------------------------------------------
__global__ __launch_bounds__(256) void gmm_main_kernel(
    const float* __restrict__ points,    // [N,16]
    const float* __restrict__ wsf,       // A-frags (40KB)
    const float* __restrict__ thr,       // [1]
    float* __restrict__ out,             // [N]
    int ntiles)
{
    __shared__ float4 A_lds4[2560];      // 40960 B

    const int tid = threadIdx.x;
    const int w   = tid >> 6;
    const int l   = tid & 63;
    const int col = l & 31;
    const bool hi = (l >> 5) != 0;

    // cooperative A fill: 2560 float4 / 256 threads = 10 each
    {
        const float4* src = (const float4*)wsf;
        #pragma unroll
        for (int i = 0; i < 10; ++i)
            A_lds4[i * 256 + tid] = src[i * 256 + tid];
    }
    __syncthreads();                     // only barrier in the kernel

    const half8* Ah = (const half8*)A_lds4 + l;
    const float thrv = thr[0];
    const float4* pbase = (const float4*)points;

    const int wid = blockIdx.x * 4 + w;
    const int nw  = GRID_MAIN * 4;       // total waves
    const int step = 2 * nw;

    int ta = wid * 2;                    // this wave's first tile of the pair
    float4 pA0, pA1, pA2, pA3, pB0, pB1, pB2, pB3;
    if (ta < ntiles) {
        const int tb = (ta + 1 < ntiles) ? ta + 1 : ta;
        const float4* pxa = pbase + ((size_t)ta * 32 + col) * 4;
        const float4* pxb = pbase + ((size_t)tb * 32 + col) * 4;
        pA0 = pxa[0]; pA1 = pxa[1]; pA2 = pxa[2]; pA3 = pxa[3];
        pB0 = pxb[0]; pB1 = pxb[1]; pB2 = pxb[2]; pB3 = pxb[3];
    }

    for (; ta < ntiles; ta += step) {
        const int  tb = ta + 1;
        const bool vb = tb < ntiles;

        // z = x - 0.5 for both tiles
        float zA[D_DIM], zB[D_DIM];
        zA[0]=pA0.x-0.5f; zA[1]=pA0.y-0.5f; zA[2]=pA0.z-0.5f; zA[3]=pA0.w-0.5f;
        zA[4]=pA1.x-0.5f; zA[5]=pA1.y-0.5f; zA[6]=pA1.z-0.5f; zA[7]=pA1.w-0.5f;
        zA[8]=pA2.x-0.5f; zA[9]=pA2.y-0.5f; zA[10]=pA2.z-0.5f; zA[11]=pA2.w-0.5f;
        zA[12]=pA3.x-0.5f; zA[13]=pA3.y-0.5f; zA[14]=pA3.z-0.5f; zA[15]=pA3.w-0.5f;
        zB[0]=pB0.x-0.5f; zB[1]=pB0.y-0.5f; zB[2]=pB0.z-0.5f; zB[3]=pB0.w-0.5f;
        zB[4]=pB1.x-0.5f; zB[5]=pB1.y-0.5f; zB[6]=pB1.z-0.5f; zB[7]=pB1.w-0.5f;
        zB[8]=pB2.x-0.5f; zB[9]=pB2.y-0.5f; zB[10]=pB2.z-0.5f; zB[11]=pB2.w-0.5f;
        zB[12]=pB3.x-0.5f; zB[13]=pB3.y-0.5f; zB[14]=pB3.z-0.5f; zB[15]=pB3.w-0.5f;

        // prefetch next pair early (hides HBM/L2 latency under compute)
        {
            const int na = ta + step;
            if (na < ntiles) {
                const int nb = (na + 1 < ntiles) ? na + 1 : na;
                const float4* pxa = pbase + ((size_t)na * 32 + col) * 4;
                const float4* pxb = pbase + ((size_t)nb * 32 + col) * 4;
                pA0 = pxa[0]; pA1 = pxa[1]; pA2 = pxa[2]; pA3 = pxa[3];
                pB0 = pxb[0]; pB1 = pxb[1]; pB2 = pxb[2]; pB3 = pxb[3];
            }
        }

        // sigma-select arrays per tile (cndmask on lane-half, no divergence)
        float zsA[16], zAl[4], zAh[4], zsB[16], zBl[4], zBh[4];
        #pragma unroll
        for (int i = 0; i < 16; ++i) {
            zsA[i] = hi ? zA[(i + 8) & 15] : zA[i];
            zsB[i] = hi ? zB[(i + 8) & 15] : zB[i];
        }
        #pragma unroll
        for (int i = 0; i < 4; ++i) {
            zAl[i] = hi ? zA[i + 4]  : zA[i];
            zAh[i] = hi ? zA[i + 12] : zA[i + 8];
            zBl[i] = hi ? zB[i + 4]  : zB[i];
            zBh[i] = hi ? zB[i + 12] : zB[i + 8];
        }

        f32x16 aA0 = {0.f,0.f,0.f,0.f,0.f,0.f,0.f,0.f,0.f,0.f,0.f,0.f,0.f,0.f,0.f,0.f};
        f32x16 aA1 = aA0, aA2 = aA0, aA3 = aA0;
        f32x16 aB0 = aA0, aB1 = aA0, aB2 = aA0, aB3 = aA0;

        #pragma unroll
        for (int t = 0; t < KSTEPS; ++t) {
            half8 bfA, bfB;
            MAKE_BF(bfA, zsA, zAl, zAh);
            MAKE_BF(bfB, zsB, zBl, zBh);

            const half8 a0 = Ah[(0 * KSTEPS + t) * 64];
            const half8 a1 = Ah[(1 * KSTEPS + t) * 64];
            const half8 a2 = Ah[(2 * KSTEPS + t) * 64];
            const half8 a3 = Ah[(3 * KSTEPS + t) * 64];
            aA0 = __builtin_amdgcn_mfma_f32_32x32x16_f16(a0, bfA, aA0, 0, 0, 0);
            aB0 = __builtin_amdgcn_mfma_f32_32x32x16_f16(a0, bfB, aB0, 0, 0, 0);
            aA1 = __builtin_amdgcn_mfma_f32_32x32x16_f16(a1, bfA, aA1, 0, 0, 0);
            aB1 = __builtin_amdgcn_mfma_f32_32x32x16_f16(a1, bfB, aB1, 0, 0, 0);
            aA2 = __builtin_amdgcn_mfma_f32_32x32x16_f16(a2, bfA, aA2, 0, 0, 0);
            aB2 = __builtin_amdgcn_mfma_f32_32x32x16_f16(a2, bfB, aB2, 0, 0, 0);
            aA3 = __builtin_amdgcn_mfma_f32_32x32x16_f16(a3, bfA, aA3, 0, 0, 0);
            aB3 = __builtin_amdgcn_mfma_f32_32x32x16_f16(a3, bfB, aB3, 0, 0, 0);
        }

        // two independent epilogues (log2 domain) — scheduler interleaves
        EPILOGUE(aA0, aA1, aA2, aA3, ta, true);
        EPILOGUE(aB0, aB1, aB2, aB3, tb, vb);
    }
}

extern "C" void kernel_launch(void* const* d_in, const int* in_sizes, int n_in,
                              void* d_out, int out_size, void* d_ws, size_t ws_size,
                              hipStream_t stream) {
    const float* points  = (const float*)d_in[0];
    const float* centers = (const float*)d_in[1];
    const float* covs    = (const float*)d_in[2];
    const float* weights = (const float*)d_in[3];
    const float* thr     = (const float*)d_in[4];
    float* out = (float*)d_out;
    float* ws  = (float*)d_ws;

    const int n      = in_sizes[0] / D_DIM;   // 500000
    const int ntiles = n / 32;                // 15625 (exact)

    gmm_prep_kernel<<<M_CTR, 64, 0, stream>>>(centers, covs, weights, ws);
    gmm_main_kernel<<<GRID_MAIN, 256, 0, stream>>>(points, ws, thr, out, ntiles);
}